// Round 9
// baseline (287.059 us; speedup 1.0000x reference)
//
#include <hip/hip_runtime.h>

typedef short bf16x8 __attribute__((ext_vector_type(8)));
typedef float f32x4 __attribute__((ext_vector_type(4)));
typedef float f32x16 __attribute__((ext_vector_type(16)));

#define AS1 __attribute__((address_space(1)))
#define AS3 __attribute__((address_space(3)))
#define GLOAD16(g, l) __builtin_amdgcn_global_load_lds((const AS1 unsigned int*)(g), (AS3 unsigned int*)(l), 16, 0, 0)

#define B_   2
#define S_   4096
#define DIM_ 1024
#define H_   16
#define HD_  64
#define BLK_ 512
#define SCLQ 0.18033688011112042f   // log2(e)/8, folded into Q

static __device__ __forceinline__ unsigned short f2bf(float x){
  unsigned int u = __builtin_bit_cast(unsigned int, x);
  u += 0x7fffu + ((u >> 16) & 1u);
  return (unsigned short)(u >> 16);
}

static __device__ __forceinline__ unsigned cvtpk(float lo, float hi){
  unsigned r;
  asm("v_cvt_pk_bf16_f32 %0, %1, %2" : "=v"(r) : "v"(lo), "v"(hi));
  return r;
}
static __device__ __forceinline__ void plswap(unsigned &a, unsigned &b){
  asm("v_permlane32_swap_b32 %0, %1" : "+v"(a), "+v"(b));
}
static __device__ __forceinline__ bf16x8 mkpa(unsigned a, unsigned b, unsigned c, unsigned d){
  int4 v = make_int4((int)a,(int)b,(int)c,(int)d);
  return __builtin_bit_cast(bf16x8, v);
}

// ---------------- x -> bf16 ----------------
__global__ __launch_bounds__(256) void k_convert_x(const float4* __restrict__ x, ushort4* __restrict__ xb){
  int i = blockIdx.x * 256 + threadIdx.x;
  float4 v = x[i];
  xb[i] = make_ushort4(f2bf(v.x), f2bf(v.y), f2bf(v.z), f2bf(v.w));
}

// ---------------- weight transpose f32 -> bf16: wqkvT[3072][1024], woT[1024][1024] ----------------
__global__ __launch_bounds__(256) void k_transpose_w(
    const float* __restrict__ w0, const float* __restrict__ w1,
    const float* __restrict__ w2, const float* __restrict__ w3,
    unsigned short* __restrict__ wqkvT, unsigned short* __restrict__ woT){
  __shared__ float tl[32][33];
  int z = blockIdx.z;
  const float* w = z==0 ? w0 : z==1 ? w1 : z==2 ? w2 : w3;
  unsigned short* t = (z==3) ? woT : (wqkvT + (size_t)z*1024*1024);
  int nb = blockIdx.x*32, kb = blockIdx.y*32;
  int tx = threadIdx.x & 31, ty = threadIdx.x >> 5;
  #pragma unroll
  for(int i=0;i<4;i++) tl[ty+8*i][tx] = w[(size_t)(kb+ty+8*i)*DIM_ + nb+tx];
  __syncthreads();
  #pragma unroll
  for(int i=0;i<4;i++) t[(size_t)(nb+ty+8*i)*DIM_ + kb+tx] = f2bf(tl[tx][ty+8*i]);
}

// ---------------- selection side path (exact f32) ----------------
__global__ __launch_bounds__(256) void k_prepw(const float* __restrict__ cosT, const float* __restrict__ sinT,
                                               float* __restrict__ W){
  int idx = blockIdx.x*256 + threadIdx.x;
  int s = idx >> 6, j = idx & 63;
  W[idx] = (j < 32) ? cosT[s*32 + j] : sinT[s*32 + j - 32];
}

__global__ __launch_bounds__(256) void k_xp(const float* __restrict__ x, const float* __restrict__ W,
                                            float* __restrict__ Xp2){
  __shared__ float Xl[16*128];   // 8 KB
  __shared__ float Wl[16*64];    // 4 KB
  int bid = blockIdx.x;
  int dt = bid & 7, ss = (bid>>3)&1, n = (bid>>4)&7, b = bid>>7;
  int tid = threadIdx.x;
  int jt = tid & 15, dtl = tid >> 4;
  int dbase = dt*128;
  int s0 = n*512 + ss*256;
  f32x4 acc[8];
  #pragma unroll
  for(int i=0;i<8;i++) acc[i] = (f32x4){0.f,0.f,0.f,0.f};

  for(int ch=0; ch<16; ch++){
    int sb = s0 + ch*16;
    #pragma unroll
    for(int i=0;i<2;i++){
      int g = i*256 + tid;
      int row = g>>5, col = g&31;
      GLOAD16(x + ((size_t)b*S_ + sb + row)*DIM_ + dbase + col*4, (char*)Xl + g*16);
    }
    {
      int row = tid>>4, col = tid&15;
      GLOAD16(W + (size_t)(sb + row)*64 + col*4, (char*)Wl + tid*16);
    }
    __syncthreads();
    #pragma unroll
    for(int s=0;s<16;s++){
      f32x4 wv = *(const f32x4*)&Wl[s*64 + jt*4];
      f32x4 x0 = *(const f32x4*)&Xl[s*128 + dtl*8];
      f32x4 x1 = *(const f32x4*)&Xl[s*128 + dtl*8 + 4];
      #pragma unroll
      for(int dd=0;dd<4;dd++) acc[dd]   += wv * x0[dd];
      #pragma unroll
      for(int dd=0;dd<4;dd++) acc[dd+4] += wv * x1[dd];
    }
    __syncthreads();
  }
  size_t base = ((size_t)(ss*16 + b*8 + n))*1024;
  #pragma unroll
  for(int dd=0;dd<8;dd++){
    size_t row = base + dbase + dtl*8 + dd;
    *(f32x4*)&Xp2[row*64 + jt*4] = acc[dd];
  }
}

__global__ __launch_bounds__(256) void k_bsum(const float* __restrict__ Xp2, const float* __restrict__ wk,
                                              float* __restrict__ bsum){
  __shared__ float red[4][64];
  int bid = blockIdx.x;
  int h = bid & 15, n = (bid>>4)&7, b = bid>>7;
  int tid = threadIdx.x;
  int jj = tid & 63, dgrp = tid >> 6;
  int j = jj & 31;
  size_t r0 = ((size_t)(b*8 + n))*1024;
  size_t r1 = ((size_t)(16 + b*8 + n))*1024;
  float acc = 0.0f;
  for(int i=0;i<256;i++){
    int d = dgrp*256 + i;
    float xc = Xp2[(r0 + d)*64 + j]      + Xp2[(r1 + d)*64 + j];
    float xs = Xp2[(r0 + d)*64 + 32 + j] + Xp2[(r1 + d)*64 + 32 + j];
    float u = wk[(size_t)d*1024 + h*64 + j];
    float v = wk[(size_t)d*1024 + h*64 + 32 + j];
    acc += (jj < 32) ? (xc*u - xs*v) : (xs*u + xc*v);
  }
  red[dgrp][jj] = acc;
  __syncthreads();
  if(tid < 64){
    float s = red[0][tid] + red[1][tid] + red[2][tid] + red[3][tid];
    bsum[(((size_t)(b*16+h))*8 + n)*64 + tid] = s;
  }
}

// 8-way K-split: 128 blocks; each reads 512KB of wq.
__global__ __launch_bounds__(256) void k_qmid(const float* __restrict__ x, const float* __restrict__ wq,
                                              float* __restrict__ qpart){
  __shared__ float xr[128];
  int bid = blockIdx.x;      // b*8+c
  int ks  = blockIdx.y;      // 0..7 k-split
  int b = bid >> 3, c = bid & 7;
  int mid = c*BLK_ + BLK_/2;
  int tid = threadIdx.x;
  if(tid < 128) xr[tid] = x[((size_t)b*S_ + mid)*DIM_ + ks*128 + tid];
  __syncthreads();
  float acc[4] = {0,0,0,0};
  for(int k=0;k<128;k++){
    float xv = xr[k];
    #pragma unroll
    for(int i=0;i<4;i++) acc[i] += xv * wq[(size_t)(ks*128+k)*1024 + i*256 + tid];
  }
  #pragma unroll
  for(int i=0;i<4;i++) qpart[((size_t)ks*16 + bid)*1024 + i*256 + tid] = acc[i];
}

__global__ __launch_bounds__(256) void k_qred(const float* __restrict__ qpart, float* __restrict__ qmid){
  int idx = blockIdx.x*256 + threadIdx.x;   // 0..16383
  float s = 0.0f;
  #pragma unroll
  for(int ks=0;ks<8;ks++) s += qpart[(size_t)ks*16384 + idx];
  qmid[idx] = s;
}

__global__ __launch_bounds__(256) void k_sel(const float* __restrict__ qmid, const float* __restrict__ bsum,
                                             const float* __restrict__ cosT, const float* __restrict__ sinT,
                                             int* __restrict__ sel){
  int bid = blockIdx.x;
  int b = bid >> 3, c = bid & 7;
  int mid = c*BLK_ + BLK_/2;
  int tid = threadIdx.x;
  int hg = tid >> 4, ln = tid & 15;
  const float* qm = qmid + (size_t)bid*1024 + hg*64;
  float rv[4];
  #pragma unroll
  for(int i=0;i<4;i++){
    int jj = ln*4 + i; int j = jj & 31;
    float q1 = qm[j], q2 = qm[32+j];
    float c0 = cosT[(size_t)mid*32 + j], s0 = sinT[(size_t)mid*32 + j];
    rv[i] = (jj < 32) ? (q1*c0 - q2*s0) : (q1*s0 + q2*c0);
  }
  float g[8];
  #pragma unroll
  for(int n=0;n<8;n++){
    const float* bs = bsum + (((size_t)(b*16+hg))*8 + n)*64 + ln*4;
    float p = rv[0]*bs[0] + rv[1]*bs[1] + rv[2]*bs[2] + rv[3]*bs[3];
    p += __shfl_xor(p,1); p += __shfl_xor(p,2); p += __shfl_xor(p,4); p += __shfl_xor(p,8);
    g[n] = p * (1.0f/512.0f) * 0.125f;
  }
  if(ln == 0){
    for(int n=c+1;n<8;n++) g[n] = -10000.0f;
    int base = ((b*16+hg)*8 + c)*3;
    #pragma unroll
    for(int t=0;t<3;t++){
      int bi = 0; float bv = g[0];
      for(int n=1;n<8;n++) if(g[n] > bv){ bv = g[n]; bi = n; }
      sel[base + t] = bi;
      g[bi] = -3.4e38f;
    }
  }
}

// ---------------- bf16 MFMA GEMM, 256x128 tile, BK=64, 8 waves, counted-vmcnt pipeline ----------------
// MODE 0: QKV fused (N=3072): sec0 rope*SCLQ -> dq, sec1 rope -> dk, sec2 V^T packed -> dv
// MODE 2: plain f32 store -> dstf
template<int MODE>
__global__ __launch_bounds__(512, 2) void k_gemmq(const unsigned short* __restrict__ A,
                                                  const unsigned short* __restrict__ Bt,
                                                  unsigned short* __restrict__ dq, unsigned short* __restrict__ dk,
                                                  unsigned short* __restrict__ dv, float* __restrict__ dstf,
                                                  const float* __restrict__ cosT, const float* __restrict__ sinT,
                                                  int M, int N, int K){
  __shared__ unsigned short lA[2][256*64];   // 64 KB, [buf][row][64k], swizzled
  __shared__ unsigned short lB[2][128*64];   // 32 KB
  int bm = blockIdx.y*256, bn = blockIdx.x*128;
  int tid = threadIdx.x, w = tid>>6, lane = tid&63;
  int wr = w>>1, wc = w&1;                   // 4M x 2N wave grid; per-wave 64x64 output
  int l15 = lane&15, lh = lane>>4;
  f32x4 acc[4][4];
  f32x4 zero = {0.f,0.f,0.f,0.f};
  #pragma unroll
  for(int m=0;m<4;m++)
    #pragma unroll
    for(int n=0;n<4;n++) acc[m][n] = zero;

  auto STAGE = [&](int bsel, int k0){
    #pragma unroll
    for(int i=0;i<4;i++){
      int g = i*512 + tid;
      int row = g>>3, slot = (g&7)^(row&7);
      GLOAD16(A + (size_t)(bm+row)*K + k0 + slot*8, (char*)lA[bsel] + g*16);
    }
    #pragma unroll
    for(int i=0;i<2;i++){
      int g = i*512 + tid;
      int row = g>>3, slot = (g&7)^(row&7);
      GLOAD16(Bt + (size_t)(bn+row)*K + k0 + slot*8, (char*)lB[bsel] + g*16);
    }
  };

  int NT = K >> 6;                 // 16 K-tiles of 64
  STAGE(0, 0);
  STAGE(1, 64);                    // 12 loads in flight
  int cur = 0;

  for(int t=0;t<NT;t++){
    if(t < NT-1) asm volatile("s_waitcnt vmcnt(6)" ::: "memory");
    else         asm volatile("s_waitcnt vmcnt(0)" ::: "memory");
    asm volatile("s_barrier" ::: "memory");

    #pragma unroll
    for(int kk=0;kk<2;kk++){
      bf16x8 af[4], bfr[4];
      #pragma unroll
      for(int m=0;m<4;m++){
        int r = wr*64 + m*16 + l15;
        af[m] = *(const bf16x8*)((const char*)lA[cur] + r*128 + (((kk*4+lh)^(r&7))*16));
      }
      #pragma unroll
      for(int n=0;n<4;n++){
        int r = wc*64 + n*16 + l15;
        bfr[n] = *(const bf16x8*)((const char*)lB[cur] + r*128 + (((kk*4+lh)^(r&7))*16));
      }
      __builtin_amdgcn_s_setprio(1);
      #pragma unroll
      for(int m=0;m<4;m++)
        #pragma unroll
        for(int n=0;n<4;n++)
          acc[m][n] = __builtin_amdgcn_mfma_f32_16x16x32_bf16(af[m], bfr[n], acc[m][n], 0, 0, 0);
      __builtin_amdgcn_s_setprio(0);
    }

    asm volatile("s_barrier" ::: "memory");
    if(t+2 < NT) STAGE(cur, (t+2)*64);
    cur ^= 1;
  }

  if(MODE == 2){
    #pragma unroll
    for(int m=0;m<4;m++){
      int row0 = bm + wr*64 + m*16 + lh*4;
      #pragma unroll
      for(int n=0;n<4;n++){
        int col = bn + wc*64 + n*16 + l15;
        #pragma unroll
        for(int r=0;r<4;r++) dstf[(size_t)(row0+r)*N + col] = acc[m][n][r];
      }
    }
  } else {
    int sec = bn >> 10;
    int nloc = (bn & 1023) + wc*64;
    if(sec == 2){
      // V^T: packed ushort4 store, dv[(b*1024+d)*4096 + s]
      #pragma unroll
      for(int m=0;m<4;m++){
        int s0 = bm + wr*64 + m*16 + lh*4;
        int bb = s0 >> 12, sl = s0 & 4095;
        #pragma unroll
        for(int n=0;n<4;n++){
          int d = nloc + n*16 + l15;
          ushort4 pk = make_ushort4(f2bf(acc[m][n][0]), f2bf(acc[m][n][1]),
                                    f2bf(acc[m][n][2]), f2bf(acc[m][n][3]));
          *(ushort4*)&dv[((size_t)(bb*1024 + d))*4096 + sl] = pk;
        }
      }
    } else {
      unsigned short* dst = (sec == 0) ? dq : dk;
      float scl = (sec == 0) ? SCLQ : 1.0f;
      int h = nloc >> 6;
      #pragma unroll
      for(int m=0;m<4;m++){
        int row0 = bm + wr*64 + m*16 + lh*4;
        #pragma unroll
        for(int n=0;n<2;n++){
          int f = n*16 + l15;
          #pragma unroll
          for(int r=0;r<4;r++){
            int row = row0 + r;
            int bb = row >> 12, s = row & 4095;
            float c0 = cosT[(size_t)s*32 + f]*scl, s0 = sinT[(size_t)s*32 + f]*scl;
            float a1 = acc[m][n][r], a2 = acc[m][n+2][r];
            size_t base = ((size_t)(bb*16 + h)*4096 + s)*64;
            dst[base + f]      = f2bf(a1*c0 - a2*s0);
            dst[base + 32 + f] = f2bf(a1*s0 + a2*c0);
          }
        }
      }
    }
  }
}

// ---------------- attention: 8 waves x 32 q (2 q-tiles merged), swapped QK^T, exp2-direct ----------------
// Round-9: round-7's merge re-run at the CORRECT register budget. Round-7 used (512,4) -> 128-cap
// and the compiler collapsed to 64 VGPR + spills (WRITE 185MB). k_gemmq proves (512,2) is
// respected (VGPR 88, no spills). (512,2): 256-VGPR cap, 2 blocks/CU, 16 waves/CU (same TLP as
// round-6's 4x256) but HALF the per-CU LDS staging volume (32 KB/tile/CU vs 64) — the dominant
// per-tile cost in the round-6/8 counter profile. Per-wave code identical to round-6.
// PASS SIGNATURE: VGPR >= ~140 and WRITE_SIZE = 16 MB. If VGPR=64 again, wide-block dedup is dead.
__global__ __launch_bounds__(512, 2) void k_attn(const unsigned short* __restrict__ q,
                                                 const unsigned short* __restrict__ kb,
                                                 const unsigned short* __restrict__ vt,
                                                 const int* __restrict__ sel,
                                                 unsigned short* __restrict__ attnb){
  __shared__ unsigned short lK[2][64*64];   // [buf][key][dim], XOR-swizzled 16B slots (8 KB each)
  __shared__ unsigned short lV[2][64*64];   // [buf][dim][key], XOR-swizzled (8 KB each)
  int cbh = blockIdx.x, q2 = blockIdx.y;
  int bh = cbh >> 3, c = cbh & 7;
  int b = bh >> 4, h = bh & 15;
  int tid = threadIdx.x, w = tid>>6, lane = tid&63;
  int ql = lane&31, hi = lane>>5;
  int q0 = c*BLK_ + q2*256 + w*32;

  const int* selp = sel + (bh*8 + c)*3;
  int sb0 = selp[0], sb1 = selp[1], sb2 = selp[2];

  // 512 threads cover one 8KB K-tile + 8KB V-tile with ONE GLOAD16 pair per thread
  int r0 = tid>>3, sl = (tid&7) ^ (r0&7);
  const unsigned short* kbase = kb + ((size_t)bh*S_ + r0)*64 + (size_t)sl*8;
  const unsigned short* vbase = vt + ((size_t)(b*1024 + h*64 + r0))*S_ + (size_t)sl*8;

  bf16x8 qf[4];
  #pragma unroll
  for(int kk=0;kk<4;kk++)
    qf[kk] = *(const bf16x8*)(q + ((size_t)bh*S_ + q0 + ql)*64 + kk*16 + hi*8);

  f32x16 o[2], o2;
  f32x16 zero16 = {0,0,0,0,0,0,0,0,0,0,0,0,0,0,0,0};
  o[0] = zero16; o[1] = zero16; o2 = zero16;
  short one_bf = (short)0x3F80;
  bf16x8 ones = {one_bf,one_bf,one_bf,one_bf,one_bf,one_bf,one_bf,one_bf};

  auto STAGE = [&](int bsel, int t){
    int seg = t>>3;
    int blk = seg==0 ? sb0 : (seg==1 ? sb1 : sb2);
    int soff = blk*BLK_ + (t&7)*64;
    GLOAD16(kbase + (size_t)soff*64, (char*)lK[bsel] + tid*16);
    GLOAD16(vbase + soff,            (char*)lV[bsel] + tid*16);
  };

  STAGE(0, 0);
  __syncthreads();
  int cur = 0;

  for(int t=0;t<24;t++){
    if(t+1 < 24) STAGE(cur^1, t+1);   // full compute(t) sits between issue and the barrier drain

    f32x16 sc[2];
    sc[0] = zero16; sc[1] = zero16;
    __builtin_amdgcn_s_setprio(1);
    #pragma unroll
    for(int g=0;g<2;g++){
      int key = g*32 + ql;
      #pragma unroll
      for(int kk=0;kk<4;kk++){
        bf16x8 kf = *(const bf16x8*)((const char*)lK[cur] + key*128 + ((kk*32 + hi*16) ^ ((ql&7)<<4)));
        sc[g] = __builtin_amdgcn_mfma_f32_32x32x16_bf16(kf, qf[kk], sc[g], 0, 0, 0);
      }
    }
    __builtin_amdgcn_s_setprio(0);

    // V fragments hoisted BEFORE exp2: LDS pipe fills the TRANS window; PV operands ready at pack
    bf16x8 vr[2][2][2];
    #pragma unroll
    for(int g=0;g<2;g++)
      #pragma unroll
      for(int dh=0;dh<2;dh++){
        int d = dh*32 + ql;
        vr[g][dh][0] = *(const bf16x8*)((const char*)lV[cur] + d*128 + ((g*64 + hi*16) ^ ((d&7)<<4)));
        vr[g][dh][1] = *(const bf16x8*)((const char*)lV[cur] + d*128 + ((g*64 + 32 + hi*16) ^ ((d&7)<<4)));
      }

    #pragma unroll
    for(int r=0;r<16;r++){
      sc[0][r] = exp2f(sc[0][r]);
      sc[1][r] = exp2f(sc[1][r]);
    }

    __builtin_amdgcn_s_setprio(1);
    #pragma unroll
    for(int g=0;g<2;g++){
      unsigned u0 = cvtpk(sc[g][0],  sc[g][1]);
      unsigned u1 = cvtpk(sc[g][4],  sc[g][5]);
      plswap(u0, u1);
      unsigned u2 = cvtpk(sc[g][2],  sc[g][3]);
      unsigned u3 = cvtpk(sc[g][6],  sc[g][7]);
      plswap(u2, u3);
      unsigned u4 = cvtpk(sc[g][8],  sc[g][9]);
      unsigned u5 = cvtpk(sc[g][12], sc[g][13]);
      plswap(u4, u5);
      unsigned u6 = cvtpk(sc[g][10], sc[g][11]);
      unsigned u7 = cvtpk(sc[g][14], sc[g][15]);
      plswap(u6, u7);
      bf16x8 pa0 = mkpa(u0,u2,u1,u3);
      bf16x8 pa1 = mkpa(u4,u6,u5,u7);
      #pragma unroll
      for(int dh=0;dh<2;dh++){
        o[dh] = __builtin_amdgcn_mfma_f32_32x32x16_bf16(pa0, vr[g][dh][0], o[dh], 0, 0, 0);
        o[dh] = __builtin_amdgcn_mfma_f32_32x32x16_bf16(pa1, vr[g][dh][1], o[dh], 0, 0, 0);
      }
      o2 = __builtin_amdgcn_mfma_f32_32x32x16_bf16(pa0, ones, o2, 0, 0, 0);
      o2 = __builtin_amdgcn_mfma_f32_32x32x16_bf16(pa1, ones, o2, 0, 0, 0);
    }
    __builtin_amdgcn_s_setprio(0);

    __syncthreads();   // single drain+barrier per tile: stage(t+1) landed, all reads of tile t done
    cur ^= 1;
  }

  #pragma unroll
  for(int r=0;r<16;r++){
    float inv = 1.0f / o2[r];
    int cr = (r&3) + 8*(r>>2) + 4*hi;
    int s = q0 + cr;
    size_t base = ((size_t)(b*S_ + s))*1024 + h*64;
    attnb[base + ql]      = f2bf(o[0][r]*inv);
    attnb[base + 32 + ql] = f2bf(o[1][r]*inv);
  }
}

extern "C" void kernel_launch(void* const* d_in, const int* in_sizes, int n_in,
                              void* d_out, int out_size, void* d_ws, size_t ws_size,
                              hipStream_t stream){
  const float* x    = (const float*)d_in[0];
  const float* wq   = (const float*)d_in[1];
  const float* wk   = (const float*)d_in[2];
  const float* wv   = (const float*)d_in[3];
  const float* wo   = (const float*)d_in[4];
  const float* cosT = (const float*)d_in[5];
  const float* sinT = (const float*)d_in[6];

  char* p = (char*)d_ws;
  unsigned short* xbf   = (unsigned short*)p; p += (size_t)8192*1024*2;
  unsigned short* wqkvT = (unsigned short*)p; p += (size_t)3072*1024*2;
  unsigned short* woT   = (unsigned short*)p; p += (size_t)1024*1024*2;
  unsigned short* qb  = (unsigned short*)p; p += (size_t)8192*1024*2;
  unsigned short* kbf = (unsigned short*)p; p += (size_t)8192*1024*2;
  unsigned short* vtb = (unsigned short*)p; p += (size_t)8192*1024*2;
  float* Wsel = (float*)p; p += (size_t)4096*64*4;
  float* Xp2  = (float*)p; p += (size_t)2*16*1024*64*4;
  float* bsum = (float*)p; p += (size_t)2*16*8*64*4;
  float* qmid = (float*)p; p += (size_t)16*1024*4;
  int*   sel  = (int*)p;   p += (size_t)2*16*8*3*4;
  unsigned short* attnb = xbf;   // alias: x_bf16 dead after the QKV GEMM
  float* qpart = Wsel;           // alias: Wsel dead after k_xp
  if((size_t)(p - (char*)d_ws) > ws_size) return;

  k_convert_x<<<8192, 256, 0, stream>>>((const float4*)x, (ushort4*)xbf);
  k_transpose_w<<<dim3(32,32,4), 256, 0, stream>>>(wq,wk,wv,wo, wqkvT, woT);
  k_prepw<<<1024, 256, 0, stream>>>(cosT, sinT, Wsel);
  k_xp<<<256, 256, 0, stream>>>(x, Wsel, Xp2);
  k_bsum<<<256, 256, 0, stream>>>(Xp2, wk, bsum);
  k_qmid<<<dim3(16,8), 256, 0, stream>>>(x, wq, qpart);
  k_qred<<<64, 256, 0, stream>>>(qpart, qmid);
  k_sel<<<16, 256, 0, stream>>>(qmid, bsum, cosT, sinT, sel);
  k_gemmq<0><<<dim3(24,32), 512, 0, stream>>>(xbf, wqkvT, qb, kbf, vtb, nullptr, cosT, sinT, 8192, 3072, 1024);
  k_attn<<<dim3(256,2), 512, 0, stream>>>(qb, kbf, vtb, sel, attnb);
  k_gemmq<2><<<dim3(8,32), 512, 0, stream>>>(attnb, woT, nullptr, nullptr, nullptr, (float*)d_out, nullptr, nullptr, 8192, 1024, 1024);
}

// Round 10
// 265.697 us; speedup vs baseline: 1.0804x; 1.0804x over previous
//
#include <hip/hip_runtime.h>

typedef short bf16x8 __attribute__((ext_vector_type(8)));
typedef float f32x4 __attribute__((ext_vector_type(4)));
typedef float f32x16 __attribute__((ext_vector_type(16)));

#define AS1 __attribute__((address_space(1)))
#define AS3 __attribute__((address_space(3)))
#define GLOAD16(g, l) __builtin_amdgcn_global_load_lds((const AS1 unsigned int*)(g), (AS3 unsigned int*)(l), 16, 0, 0)

#define B_   2
#define S_   4096
#define DIM_ 1024
#define H_   16
#define HD_  64
#define BLK_ 512
#define SCLQ 0.18033688011112042f   // log2(e)/8, folded into Q

static __device__ __forceinline__ unsigned short f2bf(float x){
  unsigned int u = __builtin_bit_cast(unsigned int, x);
  u += 0x7fffu + ((u >> 16) & 1u);
  return (unsigned short)(u >> 16);
}

static __device__ __forceinline__ unsigned cvtpk(float lo, float hi){
  unsigned r;
  asm("v_cvt_pk_bf16_f32 %0, %1, %2" : "=v"(r) : "v"(lo), "v"(hi));
  return r;
}
static __device__ __forceinline__ void plswap(unsigned &a, unsigned &b){
  asm("v_permlane32_swap_b32 %0, %1" : "+v"(a), "+v"(b));
}
static __device__ __forceinline__ bf16x8 mkpa(unsigned a, unsigned b, unsigned c, unsigned d){
  int4 v = make_int4((int)a,(int)b,(int)c,(int)d);
  return __builtin_bit_cast(bf16x8, v);
}

// ---------------- x -> bf16 ----------------
__global__ __launch_bounds__(256) void k_convert_x(const float4* __restrict__ x, ushort4* __restrict__ xb){
  int i = blockIdx.x * 256 + threadIdx.x;
  float4 v = x[i];
  xb[i] = make_ushort4(f2bf(v.x), f2bf(v.y), f2bf(v.z), f2bf(v.w));
}

// ---------------- weight transpose f32 -> bf16: wqkvT[3072][1024], woT[1024][1024] ----------------
__global__ __launch_bounds__(256) void k_transpose_w(
    const float* __restrict__ w0, const float* __restrict__ w1,
    const float* __restrict__ w2, const float* __restrict__ w3,
    unsigned short* __restrict__ wqkvT, unsigned short* __restrict__ woT){
  __shared__ float tl[32][33];
  int z = blockIdx.z;
  const float* w = z==0 ? w0 : z==1 ? w1 : z==2 ? w2 : w3;
  unsigned short* t = (z==3) ? woT : (wqkvT + (size_t)z*1024*1024);
  int nb = blockIdx.x*32, kb = blockIdx.y*32;
  int tx = threadIdx.x & 31, ty = threadIdx.x >> 5;
  #pragma unroll
  for(int i=0;i<4;i++) tl[ty+8*i][tx] = w[(size_t)(kb+ty+8*i)*DIM_ + nb+tx];
  __syncthreads();
  #pragma unroll
  for(int i=0;i<4;i++) t[(size_t)(nb+ty+8*i)*DIM_ + kb+tx] = f2bf(tl[tx][ty+8*i]);
}

// ---------------- selection side path (exact f32) ----------------
__global__ __launch_bounds__(256) void k_prepw(const float* __restrict__ cosT, const float* __restrict__ sinT,
                                               float* __restrict__ W){
  int idx = blockIdx.x*256 + threadIdx.x;
  int s = idx >> 6, j = idx & 63;
  W[idx] = (j < 32) ? cosT[s*32 + j] : sinT[s*32 + j - 32];
}

__global__ __launch_bounds__(256) void k_xp(const float* __restrict__ x, const float* __restrict__ W,
                                            float* __restrict__ Xp2){
  __shared__ float Xl[16*128];   // 8 KB
  __shared__ float Wl[16*64];    // 4 KB
  int bid = blockIdx.x;
  int dt = bid & 7, ss = (bid>>3)&1, n = (bid>>4)&7, b = bid>>7;
  int tid = threadIdx.x;
  int jt = tid & 15, dtl = tid >> 4;
  int dbase = dt*128;
  int s0 = n*512 + ss*256;
  f32x4 acc[8];
  #pragma unroll
  for(int i=0;i<8;i++) acc[i] = (f32x4){0.f,0.f,0.f,0.f};

  for(int ch=0; ch<16; ch++){
    int sb = s0 + ch*16;
    #pragma unroll
    for(int i=0;i<2;i++){
      int g = i*256 + tid;
      int row = g>>5, col = g&31;
      GLOAD16(x + ((size_t)b*S_ + sb + row)*DIM_ + dbase + col*4, (char*)Xl + g*16);
    }
    {
      int row = tid>>4, col = tid&15;
      GLOAD16(W + (size_t)(sb + row)*64 + col*4, (char*)Wl + tid*16);
    }
    __syncthreads();
    #pragma unroll
    for(int s=0;s<16;s++){
      f32x4 wv = *(const f32x4*)&Wl[s*64 + jt*4];
      f32x4 x0 = *(const f32x4*)&Xl[s*128 + dtl*8];
      f32x4 x1 = *(const f32x4*)&Xl[s*128 + dtl*8 + 4];
      #pragma unroll
      for(int dd=0;dd<4;dd++) acc[dd]   += wv * x0[dd];
      #pragma unroll
      for(int dd=0;dd<4;dd++) acc[dd+4] += wv * x1[dd];
    }
    __syncthreads();
  }
  size_t base = ((size_t)(ss*16 + b*8 + n))*1024;
  #pragma unroll
  for(int dd=0;dd<8;dd++){
    size_t row = base + dbase + dtl*8 + dd;
    *(f32x4*)&Xp2[row*64 + jt*4] = acc[dd];
  }
}

__global__ __launch_bounds__(256) void k_bsum(const float* __restrict__ Xp2, const float* __restrict__ wk,
                                              float* __restrict__ bsum){
  __shared__ float red[4][64];
  int bid = blockIdx.x;
  int h = bid & 15, n = (bid>>4)&7, b = bid>>7;
  int tid = threadIdx.x;
  int jj = tid & 63, dgrp = tid >> 6;
  int j = jj & 31;
  size_t r0 = ((size_t)(b*8 + n))*1024;
  size_t r1 = ((size_t)(16 + b*8 + n))*1024;
  float acc = 0.0f;
  for(int i=0;i<256;i++){
    int d = dgrp*256 + i;
    float xc = Xp2[(r0 + d)*64 + j]      + Xp2[(r1 + d)*64 + j];
    float xs = Xp2[(r0 + d)*64 + 32 + j] + Xp2[(r1 + d)*64 + 32 + j];
    float u = wk[(size_t)d*1024 + h*64 + j];
    float v = wk[(size_t)d*1024 + h*64 + 32 + j];
    acc += (jj < 32) ? (xc*u - xs*v) : (xs*u + xc*v);
  }
  red[dgrp][jj] = acc;
  __syncthreads();
  if(tid < 64){
    float s = red[0][tid] + red[1][tid] + red[2][tid] + red[3][tid];
    bsum[(((size_t)(b*16+h))*8 + n)*64 + tid] = s;
  }
}

// 8-way K-split: 128 blocks; each reads 512KB of wq.
__global__ __launch_bounds__(256) void k_qmid(const float* __restrict__ x, const float* __restrict__ wq,
                                              float* __restrict__ qpart){
  __shared__ float xr[128];
  int bid = blockIdx.x;      // b*8+c
  int ks  = blockIdx.y;      // 0..7 k-split
  int b = bid >> 3, c = bid & 7;
  int mid = c*BLK_ + BLK_/2;
  int tid = threadIdx.x;
  if(tid < 128) xr[tid] = x[((size_t)b*S_ + mid)*DIM_ + ks*128 + tid];
  __syncthreads();
  float acc[4] = {0,0,0,0};
  for(int k=0;k<128;k++){
    float xv = xr[k];
    #pragma unroll
    for(int i=0;i<4;i++) acc[i] += xv * wq[(size_t)(ks*128+k)*1024 + i*256 + tid];
  }
  #pragma unroll
  for(int i=0;i<4;i++) qpart[((size_t)ks*16 + bid)*1024 + i*256 + tid] = acc[i];
}

// k_sel now sums the 8 qpart partials inline (k_qred merged away)
__global__ __launch_bounds__(256) void k_sel(const float* __restrict__ qpart, const float* __restrict__ bsum,
                                             const float* __restrict__ cosT, const float* __restrict__ sinT,
                                             int* __restrict__ sel){
  int bid = blockIdx.x;
  int b = bid >> 3, c = bid & 7;
  int mid = c*BLK_ + BLK_/2;
  int tid = threadIdx.x;
  int hg = tid >> 4, ln = tid & 15;
  size_t qb0 = (size_t)bid*1024 + hg*64;
  auto qsum = [&](int idx){
    float s = 0.0f;
    #pragma unroll
    for(int ks=0;ks<8;ks++) s += qpart[(size_t)ks*16384 + qb0 + idx];
    return s;
  };
  float rv[4];
  #pragma unroll
  for(int i=0;i<4;i++){
    int jj = ln*4 + i; int j = jj & 31;
    float q1 = qsum(j), q2 = qsum(32+j);
    float c0 = cosT[(size_t)mid*32 + j], s0 = sinT[(size_t)mid*32 + j];
    rv[i] = (jj < 32) ? (q1*c0 - q2*s0) : (q1*s0 + q2*c0);
  }
  float g[8];
  #pragma unroll
  for(int n=0;n<8;n++){
    const float* bs = bsum + (((size_t)(b*16+hg))*8 + n)*64 + ln*4;
    float p = rv[0]*bs[0] + rv[1]*bs[1] + rv[2]*bs[2] + rv[3]*bs[3];
    p += __shfl_xor(p,1); p += __shfl_xor(p,2); p += __shfl_xor(p,4); p += __shfl_xor(p,8);
    g[n] = p * (1.0f/512.0f) * 0.125f;
  }
  if(ln == 0){
    for(int n=c+1;n<8;n++) g[n] = -10000.0f;
    int base = ((b*16+hg)*8 + c)*3;
    #pragma unroll
    for(int t=0;t<3;t++){
      int bi = 0; float bv = g[0];
      for(int n=1;n<8;n++) if(g[n] > bv){ bv = g[n]; bi = n; }
      sel[base + t] = bi;
      g[bi] = -3.4e38f;
    }
  }
}

// ---------------- bf16 MFMA GEMM, 128x128 tile, BK=64, 8 waves (4M x 2N), counted-vmcnt ----------------
// Round-10: 256x128/96KB was 1 block/CU -> all 8 waves stall together at every vmcnt+barrier.
// 128x128/64KB -> 2 blocks/CU: the second block's compute fills the first's stall windows.
// Same proven schedule: prologue 2 stages (8 loads in flight), in-loop wait vmcnt(4) (tile t+1's
// 4 loads stay in flight across the barrier), STAGE(t+2) after the second barrier, drain-0 only
// on the last tile. Wave tile 32x64: full 64-col head per wave -> rope epilogue carries over.
// MODE 0: QKV fused (N=3072): sec0 rope*SCLQ -> dq, sec1 rope -> dk, sec2 V^T packed -> dv
// MODE 2: plain f32 store -> dstf
template<int MODE>
__global__ __launch_bounds__(512, 2) void k_gemmq(const unsigned short* __restrict__ A,
                                                  const unsigned short* __restrict__ Bt,
                                                  unsigned short* __restrict__ dq, unsigned short* __restrict__ dk,
                                                  unsigned short* __restrict__ dv, float* __restrict__ dstf,
                                                  const float* __restrict__ cosT, const float* __restrict__ sinT,
                                                  int M, int N, int K){
  __shared__ unsigned short lA[2][128*64];   // 32 KB, [buf][row][64k], swizzled
  __shared__ unsigned short lB[2][128*64];   // 32 KB
  int bm = blockIdx.y*128, bn = blockIdx.x*128;
  int tid = threadIdx.x, w = tid>>6, lane = tid&63;
  int wr = w>>1, wc = w&1;                   // 4M x 2N wave grid; per-wave 32x64 output
  int l15 = lane&15, lh = lane>>4;
  f32x4 acc[2][4];
  f32x4 zero = {0.f,0.f,0.f,0.f};
  #pragma unroll
  for(int m=0;m<2;m++)
    #pragma unroll
    for(int n=0;n<4;n++) acc[m][n] = zero;

  // 4 GLOAD16/thread per K-tile (2 A + 2 B); source pre-swizzled slot = (g&7)^(row&7)
  auto STAGE = [&](int bsel, int k0){
    #pragma unroll
    for(int i=0;i<2;i++){
      int g = i*512 + tid;
      int row = g>>3, slot = (g&7)^(row&7);
      GLOAD16(A  + (size_t)(bm+row)*K + k0 + slot*8, (char*)lA[bsel] + g*16);
      GLOAD16(Bt + (size_t)(bn+row)*K + k0 + slot*8, (char*)lB[bsel] + g*16);
    }
  };

  int NT = K >> 6;                 // 16 K-tiles of 64
  STAGE(0, 0);
  STAGE(1, 64);                    // 8 loads in flight
  int cur = 0;

  for(int t=0;t<NT;t++){
    if(t < NT-1) asm volatile("s_waitcnt vmcnt(4)" ::: "memory");   // tile t landed; t+1 in flight
    else         asm volatile("s_waitcnt vmcnt(0)" ::: "memory");
    asm volatile("s_barrier" ::: "memory");

    #pragma unroll
    for(int kk=0;kk<2;kk++){
      bf16x8 af[2], bfr[4];
      #pragma unroll
      for(int m=0;m<2;m++){
        int r = wr*32 + m*16 + l15;
        af[m] = *(const bf16x8*)((const char*)lA[cur] + r*128 + (((kk*4+lh)^(r&7))*16));
      }
      #pragma unroll
      for(int n=0;n<4;n++){
        int r = wc*64 + n*16 + l15;
        bfr[n] = *(const bf16x8*)((const char*)lB[cur] + r*128 + (((kk*4+lh)^(r&7))*16));
      }
      __builtin_amdgcn_s_setprio(1);
      #pragma unroll
      for(int m=0;m<2;m++)
        #pragma unroll
        for(int n=0;n<4;n++)
          acc[m][n] = __builtin_amdgcn_mfma_f32_16x16x32_bf16(af[m], bfr[n], acc[m][n], 0, 0, 0);
      __builtin_amdgcn_s_setprio(0);
    }

    asm volatile("s_barrier" ::: "memory");
    if(t+2 < NT) STAGE(cur, (t+2)*64);
    cur ^= 1;
  }

  if(MODE == 2){
    #pragma unroll
    for(int m=0;m<2;m++){
      int row0 = bm + wr*32 + m*16 + lh*4;
      #pragma unroll
      for(int n=0;n<4;n++){
        int col = bn + wc*64 + n*16 + l15;
        #pragma unroll
        for(int r=0;r<4;r++) dstf[(size_t)(row0+r)*N + col] = acc[m][n][r];
      }
    }
  } else {
    int sec = bn >> 10;
    int nloc = (bn & 1023) + wc*64;
    if(sec == 2){
      // V^T: packed ushort4 store, dv[(b*1024+d)*4096 + s]
      #pragma unroll
      for(int m=0;m<2;m++){
        int s0 = bm + wr*32 + m*16 + lh*4;
        int bb = s0 >> 12, sl = s0 & 4095;
        #pragma unroll
        for(int n=0;n<4;n++){
          int d = nloc + n*16 + l15;
          ushort4 pk = make_ushort4(f2bf(acc[m][n][0]), f2bf(acc[m][n][1]),
                                    f2bf(acc[m][n][2]), f2bf(acc[m][n][3]));
          *(ushort4*)&dv[((size_t)(bb*1024 + d))*4096 + sl] = pk;
        }
      }
    } else {
      unsigned short* dst = (sec == 0) ? dq : dk;
      float scl = (sec == 0) ? SCLQ : 1.0f;
      int h = nloc >> 6;
      #pragma unroll
      for(int m=0;m<2;m++){
        int row0 = bm + wr*32 + m*16 + lh*4;
        #pragma unroll
        for(int n=0;n<2;n++){
          int f = n*16 + l15;
          #pragma unroll
          for(int r=0;r<4;r++){
            int row = row0 + r;
            int bb = row >> 12, s = row & 4095;
            float c0 = cosT[(size_t)s*32 + f]*scl, s0 = sinT[(size_t)s*32 + f]*scl;
            float a1 = acc[m][n][r], a2 = acc[m][n+2][r];
            size_t base = ((size_t)(bb*16 + h)*4096 + s)*64;
            dst[base + f]      = f2bf(a1*c0 - a2*s0);
            dst[base + 32 + f] = f2bf(a1*s0 + a2*c0);
          }
        }
      }
    }
  }
}

// ---------------- attention: 4 waves x 32 q, swapped QK^T, exp2-direct, L via ones-MFMA ----------------
// ROUND-6 CHAMPION, byte-exact revert (90.2 us). Six variants (dbuf-64KB, split-vmcnt, 3-buf,
// 512-thr merge x2) all landed 95-145 us: this shape (256 thr, 4 blocks/CU, 32 KB dbuf, one
// drain per tile) is the local optimum. KERNEL RULE: k_attn stays 256 threads.
__global__ __launch_bounds__(256, 4) void k_attn(const unsigned short* __restrict__ q,
                                                 const unsigned short* __restrict__ kb,
                                                 const unsigned short* __restrict__ vt,
                                                 const int* __restrict__ sel,
                                                 unsigned short* __restrict__ attnb){
  __shared__ unsigned short lK[2][64*64];   // [buf][key][dim], XOR-swizzled 16B slots (8 KB each)
  __shared__ unsigned short lV[2][64*64];   // [buf][dim][key], XOR-swizzled (8 KB each)
  int cbh = blockIdx.x, qt = blockIdx.y;
  int bh = cbh >> 3, c = cbh & 7;
  int b = bh >> 4, h = bh & 15;
  int tid = threadIdx.x, w = tid>>6, lane = tid&63;
  int ql = lane&31, hi = lane>>5;
  int q0 = c*BLK_ + qt*128 + w*32;

  const int* selp = sel + (bh*8 + c)*3;
  int sb0 = selp[0], sb1 = selp[1], sb2 = selp[2];

  int r0 = tid>>3, sl = (tid&7) ^ (r0&7);
  const unsigned short* kbase = kb + ((size_t)bh*S_ + r0)*64 + (size_t)sl*8;
  const unsigned short* vbase = vt + ((size_t)(b*1024 + h*64 + r0))*S_ + (size_t)sl*8;

  bf16x8 qf[4];
  #pragma unroll
  for(int kk=0;kk<4;kk++)
    qf[kk] = *(const bf16x8*)(q + ((size_t)bh*S_ + q0 + ql)*64 + kk*16 + hi*8);

  f32x16 o[2], o2;
  f32x16 zero16 = {0,0,0,0,0,0,0,0,0,0,0,0,0,0,0,0};
  o[0] = zero16; o[1] = zero16; o2 = zero16;
  short one_bf = (short)0x3F80;
  bf16x8 ones = {one_bf,one_bf,one_bf,one_bf,one_bf,one_bf,one_bf,one_bf};

  auto STAGE = [&](int bsel, int t){
    int seg = t>>3;
    int blk = seg==0 ? sb0 : (seg==1 ? sb1 : sb2);
    int soff = blk*BLK_ + (t&7)*64;
    #pragma unroll
    for(int i=0;i<2;i++){
      GLOAD16(kbase + (size_t)(soff + i*32)*64, (char*)lK[bsel] + (i*256 + w*64)*16);
      GLOAD16(vbase + (size_t)i*32*S_ + soff,   (char*)lV[bsel] + (i*256 + w*64)*16);
    }
  };

  STAGE(0, 0);
  __syncthreads();
  int cur = 0;

  for(int t=0;t<24;t++){
    if(t+1 < 24) STAGE(cur^1, t+1);

    f32x16 sc[2];
    sc[0] = zero16; sc[1] = zero16;
    __builtin_amdgcn_s_setprio(1);
    #pragma unroll
    for(int g=0;g<2;g++){
      int key = g*32 + ql;
      #pragma unroll
      for(int kk=0;kk<4;kk++){
        bf16x8 kf = *(const bf16x8*)((const char*)lK[cur] + key*128 + ((kk*32 + hi*16) ^ ((ql&7)<<4)));
        sc[g] = __builtin_amdgcn_mfma_f32_32x32x16_bf16(kf, qf[kk], sc[g], 0, 0, 0);
      }
    }
    __builtin_amdgcn_s_setprio(0);

    #pragma unroll
    for(int r=0;r<16;r++){
      sc[0][r] = exp2f(sc[0][r]);
      sc[1][r] = exp2f(sc[1][r]);
    }

    __builtin_amdgcn_s_setprio(1);
    #pragma unroll
    for(int g=0;g<2;g++){
      unsigned u0 = cvtpk(sc[g][0],  sc[g][1]);
      unsigned u1 = cvtpk(sc[g][4],  sc[g][5]);
      plswap(u0, u1);
      unsigned u2 = cvtpk(sc[g][2],  sc[g][3]);
      unsigned u3 = cvtpk(sc[g][6],  sc[g][7]);
      plswap(u2, u3);
      unsigned u4 = cvtpk(sc[g][8],  sc[g][9]);
      unsigned u5 = cvtpk(sc[g][12], sc[g][13]);
      plswap(u4, u5);
      unsigned u6 = cvtpk(sc[g][10], sc[g][11]);
      unsigned u7 = cvtpk(sc[g][14], sc[g][15]);
      plswap(u6, u7);
      bf16x8 pa0 = mkpa(u0,u2,u1,u3);
      bf16x8 pa1 = mkpa(u4,u6,u5,u7);
      #pragma unroll
      for(int dh=0;dh<2;dh++){
        int d = dh*32 + ql;
        bf16x8 v0 = *(const bf16x8*)((const char*)lV[cur] + d*128 + ((g*64 + hi*16) ^ ((d&7)<<4)));
        o[dh] = __builtin_amdgcn_mfma_f32_32x32x16_bf16(pa0, v0, o[dh], 0, 0, 0);
        bf16x8 v1 = *(const bf16x8*)((const char*)lV[cur] + d*128 + ((g*64 + 32 + hi*16) ^ ((d&7)<<4)));
        o[dh] = __builtin_amdgcn_mfma_f32_32x32x16_bf16(pa1, v1, o[dh], 0, 0, 0);
      }
      o2 = __builtin_amdgcn_mfma_f32_32x32x16_bf16(pa0, ones, o2, 0, 0, 0);
      o2 = __builtin_amdgcn_mfma_f32_32x32x16_bf16(pa1, ones, o2, 0, 0, 0);
    }
    __builtin_amdgcn_s_setprio(0);

    __syncthreads();
    cur ^= 1;
  }

  #pragma unroll
  for(int r=0;r<16;r++){
    float inv = 1.0f / o2[r];
    int cr = (r&3) + 8*(r>>2) + 4*hi;
    int s = q0 + cr;
    size_t base = ((size_t)(b*S_ + s))*1024 + h*64;
    attnb[base + ql]      = f2bf(o[0][r]*inv);
    attnb[base + 32 + ql] = f2bf(o[1][r]*inv);
  }
}

extern "C" void kernel_launch(void* const* d_in, const int* in_sizes, int n_in,
                              void* d_out, int out_size, void* d_ws, size_t ws_size,
                              hipStream_t stream){
  const float* x    = (const float*)d_in[0];
  const float* wq   = (const float*)d_in[1];
  const float* wk   = (const float*)d_in[2];
  const float* wv   = (const float*)d_in[3];
  const float* wo   = (const float*)d_in[4];
  const float* cosT = (const float*)d_in[5];
  const float* sinT = (const float*)d_in[6];

  char* p = (char*)d_ws;
  unsigned short* xbf   = (unsigned short*)p; p += (size_t)8192*1024*2;
  unsigned short* wqkvT = (unsigned short*)p; p += (size_t)3072*1024*2;
  unsigned short* woT   = (unsigned short*)p; p += (size_t)1024*1024*2;
  unsigned short* qb  = (unsigned short*)p; p += (size_t)8192*1024*2;
  unsigned short* kbf = (unsigned short*)p; p += (size_t)8192*1024*2;
  unsigned short* vtb = (unsigned short*)p; p += (size_t)8192*1024*2;
  float* Wsel = (float*)p; p += (size_t)4096*64*4;
  float* Xp2  = (float*)p; p += (size_t)2*16*1024*64*4;
  float* bsum = (float*)p; p += (size_t)2*16*8*64*4;
  float* qmid = (float*)p; p += (size_t)16*1024*4;
  int*   sel  = (int*)p;   p += (size_t)2*16*8*3*4;
  unsigned short* attnb = xbf;   // alias: x_bf16 dead after the QKV GEMM
  float* qpart = Wsel;           // alias: Wsel dead after k_xp; 512 KB <= 1 MB
  if((size_t)(p - (char*)d_ws) > ws_size) return;

  k_convert_x<<<8192, 256, 0, stream>>>((const float4*)x, (ushort4*)xbf);
  k_transpose_w<<<dim3(32,32,4), 256, 0, stream>>>(wq,wk,wv,wo, wqkvT, woT);
  k_prepw<<<1024, 256, 0, stream>>>(cosT, sinT, Wsel);
  k_xp<<<256, 256, 0, stream>>>(x, Wsel, Xp2);
  k_bsum<<<256, 256, 0, stream>>>(Xp2, wk, bsum);
  k_qmid<<<dim3(16,8), 256, 0, stream>>>(x, wq, qpart);
  k_sel<<<16, 256, 0, stream>>>(qpart, bsum, cosT, sinT, sel);
  k_gemmq<0><<<dim3(24,64), 512, 0, stream>>>(xbf, wqkvT, qb, kbf, vtb, nullptr, cosT, sinT, 8192, 3072, 1024);
  k_attn<<<dim3(256,4), 256, 0, stream>>>(qb, kbf, vtb, sel, attnb);
  k_gemmq<2><<<dim3(8,64), 512, 0, stream>>>(attnb, woT, nullptr, nullptr, nullptr, (float*)d_out, nullptr, nullptr, 8192, 1024, 1024);
}